// Round 3
// baseline (928.567 us; speedup 1.0000x reference)
//
#include <hip/hip_runtime.h>

// ---- problem constants (from reference) ----
#define SEQ      10688      // IMG_LEN + TEXT_LEN
#define IMG_LEN  10368      // 18*24*24
#define TEXT_LEN 320
#define DH       128
#define NHEADS   4
#define SLAB     3456       // 6*24*24 tokens per time-slab
#define KVC      64         // kv chunk rows
#define QTILE    64         // q rows per block (4 waves x 16)
#define NIMGT    162        // IMG_LEN/QTILE image q-tiles per head
#define NTXTT    5          // TEXT_LEN/QTILE text q-tiles per head
// (1/sqrt(128)) * log2(e): QK^T scores land in log2 domain -> exp2f softmax
#define SCALEL2E 0.12751744518924593f

// split-K config
#define TSPLIT   4          // text tile splits (167 chunks -> 42/42/42/41)
#define ISPLIT   2          // image tile splits (59 chunks -> 30/29)
#define NTXTB    (NHEADS * NTXTT * TSPLIT)            // 80
#define NIMGB    (NHEADS * NIMGT * ISPLIT)            // 1296
#define NPID     (NTXTB + NIMGB)                      // 1376
#define WS_OP_FLOATS   ((size_t)NPID * QTILE * DH)    // unnormalized O partials
#define WS_ML_FLOATS   ((size_t)NPID * QTILE * 2)     // (m, l) per row

typedef __bf16 bf16x8 __attribute__((ext_vector_type(8)));
typedef float  f32x4  __attribute__((ext_vector_type(4)));

__device__ __forceinline__ unsigned pk2bf(float a, float b) {
    union { __bf16 h[2]; unsigned u; } t;
    t.h[0] = (__bf16)a; t.h[1] = (__bf16)b;
    return t.u;
}

template<bool SPLIT>
__global__ __launch_bounds__(256, 4) void sta_attn(const float* __restrict__ Qg,
                                                   const float* __restrict__ Kg,
                                                   const float* __restrict__ Vg,
                                                   float* __restrict__ Og,
                                                   float* __restrict__ Opart,
                                                   float* __restrict__ Ml) {
    // XOR-swizzled (16B slot ^ (row&7)), SINGLE buffer (reg-staging covers overlap).
    __shared__ __align__(16) unsigned short LK[KVC * DH];   // K   [kv][d]
    __shared__ __align__(16) unsigned short VT[DH * KVC];   // V^T [d][kv]

    const int tid  = threadIdx.x;
    const int lane = tid & 63;
    const int wv   = tid >> 6;
    const int q    = lane & 15;       // query row within wave's 16
    const int g    = lane >> 4;       // lane group 0..3
    const int swq  = (q & 7) << 3;    // element-granule read swizzle

    int b = blockIdx.x;
    int head, qbase, nch, ch0, kvb0, pid = 0;
    bool isText;
    if constexpr (SPLIT) {
        if (b < NTXTB) {                       // text splits first (longest)
            int tb = b >> 2, s = b & 3;
            head = tb / NTXTT; qbase = IMG_LEN + (tb % NTXTT) * QTILE;
            isText = true; kvb0 = 0;
            ch0 = s * 42; nch = (s < 3) ? 42 : 41;
            pid = b;
        } else {
            int bb = b - NTXTB; int tile = bb >> 1, s = bb & 1;
            head = tile / NIMGT; qbase = (tile % NIMGT) * QTILE;
            isText = false; kvb0 = (qbase / SLAB) * SLAB;
            ch0 = s ? 30 : 0; nch = s ? 29 : 30;
            pid = NTXTB + bb;
        }
    } else {
        if (b < NHEADS * NTXTT) {
            head = b / NTXTT; qbase = IMG_LEN + (b % NTXTT) * QTILE;
            isText = true; ch0 = 0; nch = SEQ / KVC; kvb0 = 0;
        } else {
            int bb = b - NHEADS * NTXTT;
            head = bb / NIMGT; qbase = (bb % NIMGT) * QTILE;
            isText = false; ch0 = 0; nch = 54 + 5;
            kvb0 = (qbase / SLAB) * SLAB;
        }
    }

    const size_t hoff = (size_t)head * SEQ * DH;
    const float* Qh = Qg + hoff;
    const float* Kh = Kg + hoff;
    const float* Vh = Vg + hoff;

    // ---- Q fragments (B-operand layout), SCALE*log2e folded in ----
    const int qrow = qbase + wv * 16 + q;
    const float* qp = Qh + (size_t)qrow * DH;
    bf16x8 qf[4];
    #pragma unroll
    for (int c = 0; c < 4; ++c) {
        float4 a = *(const float4*)(qp + c * 32 + g * 8);
        float4 d = *(const float4*)(qp + c * 32 + g * 8 + 4);
        union { unsigned u[4]; bf16x8 v; } t;
        t.u[0] = pk2bf(a.x * SCALEL2E, a.y * SCALEL2E);
        t.u[1] = pk2bf(a.z * SCALEL2E, a.w * SCALEL2E);
        t.u[2] = pk2bf(d.x * SCALEL2E, d.y * SCALEL2E);
        t.u[3] = pk2bf(d.z * SCALEL2E, d.w * SCALEL2E);
        qf[c] = t.v;
    }

    f32x4 o[8];
    #pragma unroll
    for (int dt = 0; dt < 8; ++dt) o[dt] = f32x4{0.f, 0.f, 0.f, 0.f};
    float mrun = -INFINITY, lsum = 0.f;

    // staging registers (raw f32; converted at WRITE time so loads fly under compute)
    float4 kreg[8];
    float  vreg[4][8];

    auto kvaddr = [&](int gch) -> int {
        return isText ? gch * KVC
                      : (gch < 54 ? kvb0 + gch * KVC : IMG_LEN + (gch - 54) * KVC);
    };

    #define ISSUE(KVBASE)                                                        \
        {   const int _kb = (KVBASE);                                            \
            _Pragma("unroll")                                                    \
            for (int s = 0; s < 8; ++s) {                                        \
                int idx = tid + (s << 8);                                        \
                int kv = idx >> 5, dq = idx & 31;                                \
                kreg[s] = *(const float4*)(Kh + (size_t)(_kb + kv) * DH + dq*4); \
            }                                                                    \
            _Pragma("unroll")                                                    \
            for (int t = 0; t < 4; ++t) {                                        \
                int idx = tid + (t << 8);                                        \
                int d = idx & 127, kvb = idx >> 7;                               \
                const float* vp = Vh + (size_t)(_kb + kvb * 8) * DH + d;         \
                _Pragma("unroll")                                                \
                for (int j = 0; j < 8; ++j) vreg[t][j] = vp[j * DH];             \
            }                                                                    \
        }

    #define WRITE()                                                              \
        {   _Pragma("unroll")                                                    \
            for (int s = 0; s < 8; ++s) {                                        \
                int idx = tid + (s << 8);                                        \
                int kv = idx >> 5, dq = idx & 31;                                \
                int off = kv * DH + ((dq * 4) ^ ((kv & 7) << 3));                \
                uint2 u; u.x = pk2bf(kreg[s].x, kreg[s].y);                      \
                         u.y = pk2bf(kreg[s].z, kreg[s].w);                      \
                *(uint2*)&LK[off] = u;                                           \
            }                                                                    \
            _Pragma("unroll")                                                    \
            for (int t = 0; t < 4; ++t) {                                        \
                int idx = tid + (t << 8);                                        \
                int d = idx & 127, kvb = idx >> 7;                               \
                int off = d * KVC + ((kvb * 8) ^ ((d & 7) << 3));                \
                uint4 u; u.x = pk2bf(vreg[t][0], vreg[t][1]);                    \
                         u.y = pk2bf(vreg[t][2], vreg[t][3]);                    \
                         u.z = pk2bf(vreg[t][4], vreg[t][5]);                    \
                         u.w = pk2bf(vreg[t][6], vreg[t][7]);                    \
                *(uint4*)&VT[off] = u;                                           \
            }                                                                    \
        }

    ISSUE(kvaddr(ch0));
    WRITE();
    __syncthreads();

    for (int ch = 0; ch < nch; ++ch) {
        if (ch + 1 < nch) ISSUE(kvaddr(ch0 + ch + 1));   // fly under this chunk's compute

        // ---- S^T = K * Q^T : lane holds S[q][kk], kk = kt*16 + g*4 + r ----
        f32x4 st[4];
        #pragma unroll
        for (int kt = 0; kt < 4; ++kt) st[kt] = f32x4{0.f, 0.f, 0.f, 0.f};
        __builtin_amdgcn_s_setprio(1);
        #pragma unroll
        for (int c = 0; c < 4; ++c) {
            #pragma unroll
            for (int kt = 0; kt < 4; ++kt) {
                bf16x8 kf = *(const bf16x8*)&LK[(kt*16 + q)*DH + ((c*32 + g*8) ^ swq)];
                st[kt] = __builtin_amdgcn_mfma_f32_16x16x32_bf16(kf, qf[c], st[kt], 0, 0, 0);
            }
        }
        __builtin_amdgcn_s_setprio(0);

        // ---- online softmax (log2 domain) ----
        float cm = -INFINITY;
        #pragma unroll
        for (int kt = 0; kt < 4; ++kt)
            #pragma unroll
            for (int r = 0; r < 4; ++r) cm = fmaxf(cm, st[kt][r]);
        cm = fmaxf(cm, __shfl_xor(cm, 16));
        cm = fmaxf(cm, __shfl_xor(cm, 32));
        float mnew = fmaxf(mrun, cm);
        float sc = exp2f(mrun - mnew);

        float p[4][4];
        float ps = 0.f;
        #pragma unroll
        for (int kt = 0; kt < 4; ++kt)
            #pragma unroll
            for (int r = 0; r < 4; ++r) {
                p[kt][r] = exp2f(st[kt][r] - mnew);
                ps += p[kt][r];
            }
        ps += __shfl_xor(ps, 16);
        ps += __shfl_xor(ps, 32);
        lsum = lsum * sc + ps;
        mrun = mnew;
        #pragma unroll
        for (int dt = 0; dt < 8; ++dt) o[dt] *= sc;

        // ---- pack P to bf16 pairs; build P^T B-fragments via in-register shuffles ----
        unsigned pk[4][2];
        #pragma unroll
        for (int kt = 0; kt < 4; ++kt) {
            pk[kt][0] = pk2bf(p[kt][0], p[kt][1]);
            pk[kt][1] = pk2bf(p[kt][2], p[kt][3]);
        }
        const int gs2  = (g & 1) << 1;
        const int srcA = gs2 * 16 + q;
        const int srcB = (gs2 + 1) * 16 + q;
        const bool hi  = (g >> 1) & 1;
        bf16x8 pf[2];
        #pragma unroll
        for (int f = 0; f < 2; ++f) {
            unsigned wA0 = __shfl((int)pk[2*f][0], srcA), xA0 = __shfl((int)pk[2*f+1][0], srcA);
            unsigned wA1 = __shfl((int)pk[2*f][1], srcA), xA1 = __shfl((int)pk[2*f+1][1], srcA);
            unsigned wB0 = __shfl((int)pk[2*f][0], srcB), xB0 = __shfl((int)pk[2*f+1][0], srcB);
            unsigned wB1 = __shfl((int)pk[2*f][1], srcB), xB1 = __shfl((int)pk[2*f+1][1], srcB);
            union { unsigned u[4]; bf16x8 v; } t;
            t.u[0] = hi ? xA0 : wA0;
            t.u[1] = hi ? xA1 : wA1;
            t.u[2] = hi ? xB0 : wB0;
            t.u[3] = hi ? xB1 : wB1;
            pf[f] = t.v;
        }

        // ---- O^T += V^T * P^T : lane holds O[q][d], d = dt*16 + g*4 + r ----
        __builtin_amdgcn_s_setprio(1);
        #pragma unroll
        for (int f = 0; f < 2; ++f) {
            #pragma unroll
            for (int dt = 0; dt < 8; ++dt) {
                bf16x8 vf = *(const bf16x8*)&VT[(dt*16 + q)*KVC + ((f*32 + g*8) ^ swq)];
                o[dt] = __builtin_amdgcn_mfma_f32_16x16x32_bf16(vf, pf[f], o[dt], 0, 0, 0);
            }
        }
        __builtin_amdgcn_s_setprio(0);

        if (ch + 1 < nch) {
            __syncthreads();       // all waves done reading LDS
            WRITE();               // vmcnt wait lands here, after loads flew under compute
            __syncthreads();
        }
    }

    if constexpr (SPLIT) {
        // ---- store unnormalized partial O + (m, l); merge kernel finalizes ----
        float* op = Opart + (size_t)pid * (QTILE * DH) + (wv * 16 + q) * DH;
        #pragma unroll
        for (int dt = 0; dt < 8; ++dt) {
            float4 v;
            v.x = o[dt][0]; v.y = o[dt][1]; v.z = o[dt][2]; v.w = o[dt][3];
            *(float4*)(op + dt * 16 + g * 4) = v;
        }
        if (g == 0) {
            Ml[(size_t)pid * (QTILE * 2) + (wv * 16 + q) * 2]     = mrun;
            Ml[(size_t)pid * (QTILE * 2) + (wv * 16 + q) * 2 + 1] = lsum;
        }
    } else {
        // ---- finalize: 64 zero-pad keys contribute exp2(0 - mrun) each ----
        const float inv = 1.f / (lsum + 64.f * exp2f(-mrun));
        float* op = Og + hoff + (size_t)qrow * DH;
        #pragma unroll
        for (int dt = 0; dt < 8; ++dt) {
            float4 v;
            v.x = o[dt][0] * inv; v.y = o[dt][1] * inv;
            v.z = o[dt][2] * inv; v.w = o[dt][3] * inv;
            *(float4*)(op + dt * 16 + g * 4) = v;
        }
    }
    #undef ISSUE
    #undef WRITE
}

__global__ __launch_bounds__(256) void sta_merge(const float* __restrict__ Opart,
                                                 const float* __restrict__ Ml,
                                                 float* __restrict__ Og) {
    const int b = blockIdx.x;             // 0..667: original q-tile
    const int t = threadIdx.x;
    int head, qbase, S, pbase;
    if (b < NHEADS * NTXTT) {
        head = b / NTXTT; qbase = IMG_LEN + (b % NTXTT) * QTILE;
        S = TSPLIT; pbase = b * TSPLIT;
    } else {
        int tile = b - NHEADS * NTXTT;
        head = tile / NIMGT; qbase = (tile % NIMGT) * QTILE;
        S = ISPLIT; pbase = NTXTB + tile * ISPLIT;
    }
    const int row = t >> 2;               // 0..63
    const int c0  = (t & 3) * 32;

    float mv[TSPLIT], lv[TSPLIT], w[TSPLIT];
    float m = -INFINITY;
    for (int s = 0; s < S; ++s) {
        mv[s] = Ml[(size_t)(pbase + s) * (QTILE * 2) + row * 2];
        lv[s] = Ml[(size_t)(pbase + s) * (QTILE * 2) + row * 2 + 1];
        m = fmaxf(m, mv[s]);
    }
    float L = 64.f * exp2f(-m);           // 64 zero-pad keys, score 0 (log2 domain)
    for (int s = 0; s < S; ++s) { w[s] = exp2f(mv[s] - m); L += w[s] * lv[s]; }
    const float inv = 1.f / L;

    float* op = Og + (size_t)head * SEQ * DH + (size_t)(qbase + row) * DH + c0;
    #pragma unroll
    for (int j = 0; j < 8; ++j) {
        float4 acc = make_float4(0.f, 0.f, 0.f, 0.f);
        for (int s = 0; s < S; ++s) {
            const float4 p = *(const float4*)(Opart + (size_t)(pbase + s) * (QTILE * DH)
                                              + row * DH + c0 + j * 4);
            acc.x += w[s] * p.x; acc.y += w[s] * p.y;
            acc.z += w[s] * p.z; acc.w += w[s] * p.w;
        }
        float4 v; v.x = acc.x * inv; v.y = acc.y * inv; v.z = acc.z * inv; v.w = acc.w * inv;
        *(float4*)(op + j * 4) = v;
    }
}

extern "C" void kernel_launch(void* const* d_in, const int* in_sizes, int n_in,
                              void* d_out, int out_size, void* d_ws, size_t ws_size,
                              hipStream_t stream) {
    const float* Qg = (const float*)d_in[0];
    const float* Kg = (const float*)d_in[1];
    const float* Vg = (const float*)d_in[2];
    float* Og = (float*)d_out;

    const size_t need = (WS_OP_FLOATS + WS_ML_FLOATS) * sizeof(float);
    if (ws_size >= need) {
        float* Opart = (float*)d_ws;
        float* Ml    = Opart + WS_OP_FLOATS;
        hipLaunchKernelGGL(sta_attn<true>, dim3(NPID), dim3(256), 0, stream,
                           Qg, Kg, Vg, Og, Opart, Ml);
        hipLaunchKernelGGL(sta_merge, dim3(NHEADS * (NTXTT + NIMGT)), dim3(256), 0, stream,
                           Opart, Ml, Og);
    } else {
        hipLaunchKernelGGL(sta_attn<false>, dim3(NHEADS * (NTXTT + NIMGT)), dim3(256), 0, stream,
                           Qg, Kg, Vg, Og, (float*)nullptr, (float*)nullptr);
    }
}

// Round 4
// 305.266 us; speedup vs baseline: 3.0418x; 3.0418x over previous
//
#include <hip/hip_runtime.h>

// ---- problem constants (from reference) ----
#define SEQ      10688      // IMG_LEN + TEXT_LEN
#define IMG_LEN  10368      // 18*24*24
#define TEXT_LEN 320
#define DH       128
#define NHEADS   4
#define SLAB     3456       // 6*24*24 tokens per time-slab
#define KVC      64         // kv chunk rows
#define QTILE    64         // q rows per block (4 waves x 16)
#define NIMGT    162        // IMG_LEN/QTILE image q-tiles per head
#define NTXTT    5          // TEXT_LEN/QTILE text q-tiles per head
// (1/sqrt(128)) * log2(e): QK^T scores land in log2 domain -> exp2f softmax
#define SCALEL2E 0.12751744518924593f

// split-K config
#define TSPLIT   4          // text tile splits (167 chunks -> 42/42/42/41)
#define ISPLIT   2          // image tile splits (59 chunks -> 30/29)
#define NTXTB    (NHEADS * NTXTT * TSPLIT)            // 80
#define NIMGB    (NHEADS * NIMGT * ISPLIT)            // 1296
#define NPID     (NTXTB + NIMGB)                      // 1376
#define WS_OP_FLOATS   ((size_t)NPID * QTILE * DH)    // unnormalized O partials
#define WS_ML_FLOATS   ((size_t)NPID * QTILE * 2)     // (m, l) per row

typedef __bf16 bf16x8 __attribute__((ext_vector_type(8)));
typedef float  f32x4  __attribute__((ext_vector_type(4)));

__device__ __forceinline__ unsigned pk2bf(float a, float b) {
    union { __bf16 h[2]; unsigned u; } t;
    t.h[0] = (__bf16)a; t.h[1] = (__bf16)b;
    return t.u;
}

// NOTE: (256,2) not (256,4)! min-waves=4 capped VGPR at 64 -> massive scratch
// spills (WRITE_SIZE 21->620MB, dur 311->928us, round 3). (256,2) -> 100 VGPR,
// zero spill; occupancy is then VGPR-capped at 16 waves/CU anyway.
template<bool SPLIT>
__global__ __launch_bounds__(256, 2) void sta_attn(const float* __restrict__ Qg,
                                                   const float* __restrict__ Kg,
                                                   const float* __restrict__ Vg,
                                                   float* __restrict__ Og,
                                                   float* __restrict__ Opart,
                                                   float* __restrict__ Ml) {
    // XOR-swizzled (16B slot ^ (row&7)), SINGLE buffer (reg-staging covers overlap).
    __shared__ __align__(16) unsigned short LK[KVC * DH];   // K   [kv][d]
    __shared__ __align__(16) unsigned short VT[DH * KVC];   // V^T [d][kv]

    const int tid  = threadIdx.x;
    const int lane = tid & 63;
    const int wv   = tid >> 6;
    const int q    = lane & 15;       // query row within wave's 16
    const int g    = lane >> 4;       // lane group 0..3
    const int swq  = (q & 7) << 3;    // element-granule read swizzle

    int b = blockIdx.x;
    int head, qbase, nch, ch0, kvb0, pid = 0;
    bool isText;
    if constexpr (SPLIT) {
        if (b < NTXTB) {                       // text splits first (longest)
            int tb = b >> 2, s = b & 3;
            head = tb / NTXTT; qbase = IMG_LEN + (tb % NTXTT) * QTILE;
            isText = true; kvb0 = 0;
            ch0 = s * 42; nch = (s < 3) ? 42 : 41;
            pid = b;
        } else {
            int bb = b - NTXTB; int tile = bb >> 1, s = bb & 1;
            head = tile / NIMGT; qbase = (tile % NIMGT) * QTILE;
            isText = false; kvb0 = (qbase / SLAB) * SLAB;
            ch0 = s ? 30 : 0; nch = s ? 29 : 30;
            pid = NTXTB + bb;
        }
    } else {
        if (b < NHEADS * NTXTT) {
            head = b / NTXTT; qbase = IMG_LEN + (b % NTXTT) * QTILE;
            isText = true; ch0 = 0; nch = SEQ / KVC; kvb0 = 0;
        } else {
            int bb = b - NHEADS * NTXTT;
            head = bb / NIMGT; qbase = (bb % NIMGT) * QTILE;
            isText = false; ch0 = 0; nch = 54 + 5;
            kvb0 = (qbase / SLAB) * SLAB;
        }
    }

    const size_t hoff = (size_t)head * SEQ * DH;
    const float* Qh = Qg + hoff;
    const float* Kh = Kg + hoff;
    const float* Vh = Vg + hoff;

    // ---- Q fragments (B-operand layout), SCALE*log2e folded in ----
    const int qrow = qbase + wv * 16 + q;
    const float* qp = Qh + (size_t)qrow * DH;
    bf16x8 qf[4];
    #pragma unroll
    for (int c = 0; c < 4; ++c) {
        float4 a = *(const float4*)(qp + c * 32 + g * 8);
        float4 d = *(const float4*)(qp + c * 32 + g * 8 + 4);
        union { unsigned u[4]; bf16x8 v; } t;
        t.u[0] = pk2bf(a.x * SCALEL2E, a.y * SCALEL2E);
        t.u[1] = pk2bf(a.z * SCALEL2E, a.w * SCALEL2E);
        t.u[2] = pk2bf(d.x * SCALEL2E, d.y * SCALEL2E);
        t.u[3] = pk2bf(d.z * SCALEL2E, d.w * SCALEL2E);
        qf[c] = t.v;
    }

    f32x4 o[8];
    #pragma unroll
    for (int dt = 0; dt < 8; ++dt) o[dt] = f32x4{0.f, 0.f, 0.f, 0.f};
    float mrun = -INFINITY, lsum = 0.f;

    // staging registers (raw f32; converted at WRITE time so loads fly under compute)
    float4 kreg[8];
    float  vreg[4][8];

    auto kvaddr = [&](int gch) -> int {
        return isText ? gch * KVC
                      : (gch < 54 ? kvb0 + gch * KVC : IMG_LEN + (gch - 54) * KVC);
    };

    #define ISSUE(KVBASE)                                                        \
        {   const int _kb = (KVBASE);                                            \
            _Pragma("unroll")                                                    \
            for (int s = 0; s < 8; ++s) {                                        \
                int idx = tid + (s << 8);                                        \
                int kv = idx >> 5, dq = idx & 31;                                \
                kreg[s] = *(const float4*)(Kh + (size_t)(_kb + kv) * DH + dq*4); \
            }                                                                    \
            _Pragma("unroll")                                                    \
            for (int t = 0; t < 4; ++t) {                                        \
                int idx = tid + (t << 8);                                        \
                int d = idx & 127, kvb = idx >> 7;                               \
                const float* vp = Vh + (size_t)(_kb + kvb * 8) * DH + d;         \
                _Pragma("unroll")                                                \
                for (int j = 0; j < 8; ++j) vreg[t][j] = vp[j * DH];             \
            }                                                                    \
        }

    #define WRITE()                                                              \
        {   _Pragma("unroll")                                                    \
            for (int s = 0; s < 8; ++s) {                                        \
                int idx = tid + (s << 8);                                        \
                int kv = idx >> 5, dq = idx & 31;                                \
                int off = kv * DH + ((dq * 4) ^ ((kv & 7) << 3));                \
                uint2 u; u.x = pk2bf(kreg[s].x, kreg[s].y);                      \
                         u.y = pk2bf(kreg[s].z, kreg[s].w);                      \
                *(uint2*)&LK[off] = u;                                           \
            }                                                                    \
            _Pragma("unroll")                                                    \
            for (int t = 0; t < 4; ++t) {                                        \
                int idx = tid + (t << 8);                                        \
                int d = idx & 127, kvb = idx >> 7;                               \
                int off = d * KVC + ((kvb * 8) ^ ((d & 7) << 3));                \
                uint4 u; u.x = pk2bf(vreg[t][0], vreg[t][1]);                    \
                         u.y = pk2bf(vreg[t][2], vreg[t][3]);                    \
                         u.z = pk2bf(vreg[t][4], vreg[t][5]);                    \
                         u.w = pk2bf(vreg[t][6], vreg[t][7]);                    \
                *(uint4*)&VT[off] = u;                                           \
            }                                                                    \
        }

    ISSUE(kvaddr(ch0));
    WRITE();
    __syncthreads();

    for (int ch = 0; ch < nch; ++ch) {
        if (ch + 1 < nch) ISSUE(kvaddr(ch0 + ch + 1));   // fly under this chunk's compute

        // ---- S^T = K * Q^T : lane holds S[q][kk], kk = kt*16 + g*4 + r ----
        f32x4 st[4];
        #pragma unroll
        for (int kt = 0; kt < 4; ++kt) st[kt] = f32x4{0.f, 0.f, 0.f, 0.f};
        __builtin_amdgcn_s_setprio(1);
        #pragma unroll
        for (int c = 0; c < 4; ++c) {
            #pragma unroll
            for (int kt = 0; kt < 4; ++kt) {
                bf16x8 kf = *(const bf16x8*)&LK[(kt*16 + q)*DH + ((c*32 + g*8) ^ swq)];
                st[kt] = __builtin_amdgcn_mfma_f32_16x16x32_bf16(kf, qf[c], st[kt], 0, 0, 0);
            }
        }
        __builtin_amdgcn_s_setprio(0);

        // ---- online softmax (log2 domain) ----
        float cm = -INFINITY;
        #pragma unroll
        for (int kt = 0; kt < 4; ++kt)
            #pragma unroll
            for (int r = 0; r < 4; ++r) cm = fmaxf(cm, st[kt][r]);
        cm = fmaxf(cm, __shfl_xor(cm, 16));
        cm = fmaxf(cm, __shfl_xor(cm, 32));
        float mnew = fmaxf(mrun, cm);
        float sc = exp2f(mrun - mnew);

        float p[4][4];
        float ps = 0.f;
        #pragma unroll
        for (int kt = 0; kt < 4; ++kt)
            #pragma unroll
            for (int r = 0; r < 4; ++r) {
                p[kt][r] = exp2f(st[kt][r] - mnew);
                ps += p[kt][r];
            }
        ps += __shfl_xor(ps, 16);
        ps += __shfl_xor(ps, 32);
        lsum = lsum * sc + ps;
        mrun = mnew;
        #pragma unroll
        for (int dt = 0; dt < 8; ++dt) o[dt] *= sc;

        // ---- pack P to bf16 pairs; build P^T B-fragments via in-register shuffles ----
        unsigned pk[4][2];
        #pragma unroll
        for (int kt = 0; kt < 4; ++kt) {
            pk[kt][0] = pk2bf(p[kt][0], p[kt][1]);
            pk[kt][1] = pk2bf(p[kt][2], p[kt][3]);
        }
        const int gs2  = (g & 1) << 1;
        const int srcA = gs2 * 16 + q;
        const int srcB = (gs2 + 1) * 16 + q;
        const bool hi  = (g >> 1) & 1;
        bf16x8 pf[2];
        #pragma unroll
        for (int f = 0; f < 2; ++f) {
            unsigned wA0 = __shfl((int)pk[2*f][0], srcA), xA0 = __shfl((int)pk[2*f+1][0], srcA);
            unsigned wA1 = __shfl((int)pk[2*f][1], srcA), xA1 = __shfl((int)pk[2*f+1][1], srcA);
            unsigned wB0 = __shfl((int)pk[2*f][0], srcB), xB0 = __shfl((int)pk[2*f+1][0], srcB);
            unsigned wB1 = __shfl((int)pk[2*f][1], srcB), xB1 = __shfl((int)pk[2*f+1][1], srcB);
            union { unsigned u[4]; bf16x8 v; } t;
            t.u[0] = hi ? xA0 : wA0;
            t.u[1] = hi ? xA1 : wA1;
            t.u[2] = hi ? xB0 : wB0;
            t.u[3] = hi ? xB1 : wB1;
            pf[f] = t.v;
        }

        // ---- O^T += V^T * P^T : lane holds O[q][d], d = dt*16 + g*4 + r ----
        __builtin_amdgcn_s_setprio(1);
        #pragma unroll
        for (int f = 0; f < 2; ++f) {
            #pragma unroll
            for (int dt = 0; dt < 8; ++dt) {
                bf16x8 vf = *(const bf16x8*)&VT[(dt*16 + q)*KVC + ((f*32 + g*8) ^ swq)];
                o[dt] = __builtin_amdgcn_mfma_f32_16x16x32_bf16(vf, pf[f], o[dt], 0, 0, 0);
            }
        }
        __builtin_amdgcn_s_setprio(0);

        if (ch + 1 < nch) {
            __syncthreads();       // all waves done reading LDS
            WRITE();               // vmcnt wait lands here, after loads flew under compute
            __syncthreads();
        }
    }

    if constexpr (SPLIT) {
        // ---- store unnormalized partial O + (m, l); merge kernel finalizes ----
        float* op = Opart + (size_t)pid * (QTILE * DH) + (wv * 16 + q) * DH;
        #pragma unroll
        for (int dt = 0; dt < 8; ++dt) {
            float4 v;
            v.x = o[dt][0]; v.y = o[dt][1]; v.z = o[dt][2]; v.w = o[dt][3];
            *(float4*)(op + dt * 16 + g * 4) = v;
        }
        if (g == 0) {
            Ml[(size_t)pid * (QTILE * 2) + (wv * 16 + q) * 2]     = mrun;
            Ml[(size_t)pid * (QTILE * 2) + (wv * 16 + q) * 2 + 1] = lsum;
        }
    } else {
        // ---- finalize: 64 zero-pad keys contribute exp2(0 - mrun) each ----
        const float inv = 1.f / (lsum + 64.f * exp2f(-mrun));
        float* op = Og + hoff + (size_t)qrow * DH;
        #pragma unroll
        for (int dt = 0; dt < 8; ++dt) {
            float4 v;
            v.x = o[dt][0] * inv; v.y = o[dt][1] * inv;
            v.z = o[dt][2] * inv; v.w = o[dt][3] * inv;
            *(float4*)(op + dt * 16 + g * 4) = v;
        }
    }
    #undef ISSUE
    #undef WRITE
}

__global__ __launch_bounds__(256) void sta_merge(const float* __restrict__ Opart,
                                                 const float* __restrict__ Ml,
                                                 float* __restrict__ Og) {
    const int b = blockIdx.x;             // 0..667: original q-tile
    const int t = threadIdx.x;
    int head, qbase, S, pbase;
    if (b < NHEADS * NTXTT) {
        head = b / NTXTT; qbase = IMG_LEN + (b % NTXTT) * QTILE;
        S = TSPLIT; pbase = b * TSPLIT;
    } else {
        int tile = b - NHEADS * NTXTT;
        head = tile / NIMGT; qbase = (tile % NIMGT) * QTILE;
        S = ISPLIT; pbase = NTXTB + tile * ISPLIT;
    }
    const int row = t >> 2;               // 0..63
    const int c0  = (t & 3) * 32;

    float mv[TSPLIT], lv[TSPLIT], w[TSPLIT];
    float m = -INFINITY;
    for (int s = 0; s < S; ++s) {
        mv[s] = Ml[(size_t)(pbase + s) * (QTILE * 2) + row * 2];
        lv[s] = Ml[(size_t)(pbase + s) * (QTILE * 2) + row * 2 + 1];
        m = fmaxf(m, mv[s]);
    }
    float L = 64.f * exp2f(-m);           // 64 zero-pad keys, score 0 (log2 domain)
    for (int s = 0; s < S; ++s) { w[s] = exp2f(mv[s] - m); L += w[s] * lv[s]; }
    const float inv = 1.f / L;

    float* op = Og + (size_t)head * SEQ * DH + (size_t)(qbase + row) * DH + c0;
    #pragma unroll
    for (int j = 0; j < 8; ++j) {
        float4 acc = make_float4(0.f, 0.f, 0.f, 0.f);
        for (int s = 0; s < S; ++s) {
            const float4 p = *(const float4*)(Opart + (size_t)(pbase + s) * (QTILE * DH)
                                              + row * DH + c0 + j * 4);
            acc.x += w[s] * p.x; acc.y += w[s] * p.y;
            acc.z += w[s] * p.z; acc.w += w[s] * p.w;
        }
        float4 v; v.x = acc.x * inv; v.y = acc.y * inv; v.z = acc.z * inv; v.w = acc.w * inv;
        *(float4*)(op + j * 4) = v;
    }
}

extern "C" void kernel_launch(void* const* d_in, const int* in_sizes, int n_in,
                              void* d_out, int out_size, void* d_ws, size_t ws_size,
                              hipStream_t stream) {
    const float* Qg = (const float*)d_in[0];
    const float* Kg = (const float*)d_in[1];
    const float* Vg = (const float*)d_in[2];
    float* Og = (float*)d_out;

    const size_t need = (WS_OP_FLOATS + WS_ML_FLOATS) * sizeof(float);
    if (ws_size >= need) {
        float* Opart = (float*)d_ws;
        float* Ml    = Opart + WS_OP_FLOATS;
        hipLaunchKernelGGL(sta_attn<true>, dim3(NPID), dim3(256), 0, stream,
                           Qg, Kg, Vg, Og, Opart, Ml);
        hipLaunchKernelGGL(sta_merge, dim3(NHEADS * (NTXTT + NIMGT)), dim3(256), 0, stream,
                           Opart, Ml, Og);
    } else {
        hipLaunchKernelGGL(sta_attn<false>, dim3(NHEADS * (NTXTT + NIMGT)), dim3(256), 0, stream,
                           Qg, Kg, Vg, Og, (float*)nullptr, (float*)nullptr);
    }
}